// Round 1
// baseline (1457.674 us; speedup 1.0000x reference)
//
#include <hip/hip_runtime.h>

// Problem constants (match reference)
#define B_    32
#define NV_   50000
#define NF_   100000
#define CCLS  40
#define GPB   32     // blocks per batch
#define TPB   256    // threads per block

__device__ __forceinline__ float fsig(float t) {
    // sigmoid(t) = 1 / (1 + exp(-t)); v_exp + v_rcp fast path
    return __builtin_amdgcn_rcpf(1.0f + __expf(-t));
}

// Kernel 1: per-face geometry + MLP layers 1-2, accumulate S[k] = sum_f h2[k]*L
// and SL = sum_f L, one partial vector [65] per block into d_ws.
__global__ __launch_bounds__(TPB, 2) void face_mlp_partial(
    const float* __restrict__ V,   // [B,NV,3]
    const int*   __restrict__ F,   // [B,NF,3]
    const float* __restrict__ W1,  // [6,16]
    const float* __restrict__ b1,  // [16]
    const float* __restrict__ W2,  // [16,64]
    const float* __restrict__ b2,  // [64]
    float* __restrict__ ws)        // [B, GPB, 65]
{
    const int b   = blockIdx.y;
    const int g   = blockIdx.x;
    const int tid = threadIdx.x;

    const float* Vb = V + (size_t)b * NV_ * 3;
    const int*   Fb = F + (size_t)b * NF_ * 3;

    float S[64];
#pragma unroll
    for (int k = 0; k < 64; ++k) S[k] = 0.f;
    float SL = 0.f;

    for (int i = g * TPB + tid; i < NF_; i += GPB * TPB) {
        const int i0 = Fb[3 * i + 0];
        const int i1 = Fb[3 * i + 1];
        const int i2 = Fb[3 * i + 2];

        const float ax = Vb[3 * i0 + 0], ay = Vb[3 * i0 + 1], az = Vb[3 * i0 + 2];
        const float bx = Vb[3 * i1 + 0], by = Vb[3 * i1 + 1], bz = Vb[3 * i1 + 2];
        const float cx = Vb[3 * i2 + 0], cy = Vb[3 * i2 + 1], cz = Vb[3 * i2 + 2];

        const float ccx = (ax + bx + cx) * (1.f / 3.f);
        const float ccy = (ay + by + cy) * (1.f / 3.f);
        const float ccz = (az + bz + cz) * (1.f / 3.f);

        const float e1x = bx - ax, e1y = by - ay, e1z = bz - az;
        const float e2x = cx - ax, e2y = cy - ay, e2z = cz - az;

        const float nx = 0.5f * (e1y * e2z - e1z * e2y);
        const float ny = 0.5f * (e1z * e2x - e1x * e2z);
        const float nz = 0.5f * (e1x * e2y - e1y * e2x);

        const float l2  = fmaxf(nx * nx + ny * ny + nz * nz, 1e-6f);
        const float rl  = __builtin_amdgcn_rsqf(l2);   // 1/sqrt(l2)
        const float L   = l2 * rl;                     // sqrt(l2)

        const float x0 = ccx, x1 = ccy, x2 = ccz;
        const float x3 = nx * rl, x4 = ny * rl, x5 = nz * rl;

        float h1[16];
#pragma unroll
        for (int j = 0; j < 16; ++j) {
            float t = b1[j];
            t = fmaf(x0, W1[0 * 16 + j], t);
            t = fmaf(x1, W1[1 * 16 + j], t);
            t = fmaf(x2, W1[2 * 16 + j], t);
            t = fmaf(x3, W1[3 * 16 + j], t);
            t = fmaf(x4, W1[4 * 16 + j], t);
            t = fmaf(x5, W1[5 * 16 + j], t);
            h1[j] = fsig(t);
        }

#pragma unroll
        for (int k = 0; k < 64; ++k) {
            float t = b2[k];
#pragma unroll
            for (int j = 0; j < 16; ++j)
                t = fmaf(h1[j], W2[j * 64 + k], t);
            S[k] = fmaf(fsig(t), L, S[k]);
        }
        SL += L;
    }

    // Deterministic reduction: wave shuffle -> LDS -> one partial per block.
#pragma unroll
    for (int k = 0; k < 64; ++k) {
#pragma unroll
        for (int off = 32; off; off >>= 1)
            S[k] += __shfl_down(S[k], off, 64);
    }
#pragma unroll
    for (int off = 32; off; off >>= 1)
        SL += __shfl_down(SL, off, 64);

    __shared__ float red[TPB / 64][65];
    const int wave = tid >> 6;
    const int lane = tid & 63;
    if (lane == 0) {
#pragma unroll
        for (int k = 0; k < 64; ++k) red[wave][k] = S[k];
        red[wave][64] = SL;
    }
    __syncthreads();

    if (tid < 65) {
        float s = 0.f;
#pragma unroll
        for (int w = 0; w < TPB / 64; ++w) s += red[w][tid];
        ws[((size_t)b * GPB + g) * 65 + tid] = s;
    }
}

// Kernel 2: fold partials through W3/b3. One thread per (b,c). Fully writes d_out.
__global__ __launch_bounds__(256) void finalize_out(
    const float* __restrict__ ws,  // [B, GPB, 65]
    const float* __restrict__ W3,  // [64, CCLS]
    const float* __restrict__ b3,  // [CCLS]
    float* __restrict__ out)       // [B, CCLS]
{
    const int t = blockIdx.x * blockDim.x + threadIdx.x;
    if (t >= B_ * CCLS) return;
    const int b = t / CCLS;
    const int c = t % CCLS;

    float acc = 0.f;
#pragma unroll 4
    for (int k = 0; k < 64; ++k) {
        float sk = 0.f;
        for (int g = 0; g < GPB; ++g)
            sk += ws[((size_t)b * GPB + g) * 65 + k];
        acc = fmaf(sk, W3[k * CCLS + c], acc);
    }
    float sl = 0.f;
    for (int g = 0; g < GPB; ++g)
        sl += ws[((size_t)b * GPB + g) * 65 + 64];
    out[t] = fmaf(b3[c], sl, acc);
}

extern "C" void kernel_launch(void* const* d_in, const int* in_sizes, int n_in,
                              void* d_out, int out_size, void* d_ws, size_t ws_size,
                              hipStream_t stream) {
    const float* V  = (const float*)d_in[0];
    const int*   F  = (const int*)  d_in[1];
    const float* W1 = (const float*)d_in[2];
    const float* b1 = (const float*)d_in[3];
    const float* W2 = (const float*)d_in[4];
    const float* b2 = (const float*)d_in[5];
    const float* W3 = (const float*)d_in[6];
    const float* b3 = (const float*)d_in[7];
    float* out = (float*)d_out;
    float* ws  = (float*)d_ws;   // needs B*GPB*65*4 = 266,240 bytes

    dim3 grid1(GPB, B_);
    face_mlp_partial<<<grid1, TPB, 0, stream>>>(V, F, W1, b1, W2, b2, ws);

    const int n2 = B_ * CCLS;
    finalize_out<<<(n2 + 255) / 256, 256, 0, stream>>>(ws, W3, b3, out);
}

// Round 2
// 147.245 us; speedup vs baseline: 9.8997x; 9.8997x over previous
//
#include <hip/hip_runtime.h>

// Problem constants (match reference)
#define B_    32
#define NV_   50000
#define NF_   100000
#define CCLS  40
#define GPB   64                       // blocks per batch
#define TPB   256
#define NTILE ((NF_ + TPB - 1) / TPB)  // 391 face-tiles per batch
#define ROW   17                       // LDS row stride: 16 h1 + L; odd => conflict-free

__device__ __forceinline__ float fsig(float t) {
    // sigmoid(t) = 1/(1+exp(-t))
    return __builtin_amdgcn_rcpf(1.0f + __expf(-t));
}

// Kernel 1: per 256-face tile: phase A/B (geometry + layer1 -> LDS),
// phase C (layer2, each thread owns 4 k-channels with W2 slice in VGPRs).
// Emits per-block partials ws[b][g][0..63]=sum h2[k]*L, ws[b][g][64]=sum L.
__global__ __launch_bounds__(TPB, 4) void face_mlp_partial(
    const float* __restrict__ V,   // [B,NV,3]
    const int*   __restrict__ F,   // [B,NF,3]
    const float* __restrict__ W1,  // [6,16]
    const float* __restrict__ b1,  // [16]
    const float* __restrict__ W2,  // [16,64]
    const float* __restrict__ b2,  // [64]
    float* __restrict__ ws)        // [B, GPB, 65]
{
    __shared__ float sh[TPB * ROW];    // h1[16]+L per face (also reused for reduce)
    __shared__ float wlds[112];        // W1 (96) + b1 (16)
    __shared__ float slred[TPB / 64];

    const int i   = blockIdx.x;
    // XCD-aware mapping: block i -> XCD (i&7); each XCD owns 4 batches so the
    // 4 x 600KB V-slices stay resident in its 4MB L2.
    const int xcd = i & 7;
    const int j   = i >> 3;            // 0..255
    const int b   = xcd + 8 * (j >> 6);
    const int g   = j & 63;            // block-within-batch
    const int tid = threadIdx.x;
    const int lane = tid & 63;
    const int wave = tid >> 6;

    const float* Vb = V + (size_t)b * NV_ * 3;
    const int*   Fb = F + (size_t)b * NF_ * 3;

    // Stage W1/b1 into LDS (broadcast reads in phase B).
    if (tid < 96)                 wlds[tid] = W1[tid];
    else if (tid < 112)           wlds[tid] = b1[tid - 96];

    // Per-thread W2 slice: k = 4*(tid&15) .. +3  (loaded ONCE).
    const int kq = tid & 15;
    const int k0 = kq * 4;
    const int fg = tid >> 4;           // face-group 0..15
    float4 w2r[16];
#pragma unroll
    for (int jj = 0; jj < 16; ++jj)
        w2r[jj] = *(const float4*)(W2 + jj * 64 + k0);
    const float4 b2r = *(const float4*)(b2 + k0);

    float S0 = 0.f, S1 = 0.f, S2 = 0.f, S3 = 0.f;
    float SL = 0.f;

    __syncthreads();

    // Uniform tile loop (uniform trip count per block -> scalarizable / no divergence)
    for (int t = g; t < NTILE; t += GPB) {
        // ---- Phase A/B: one face per thread ----
        const int f     = t * TPB + tid;
        const bool valid = (f < NF_);
        const int fi    = valid ? f : 0;

        const int i0 = Fb[3 * fi + 0];
        const int i1 = Fb[3 * fi + 1];
        const int i2 = Fb[3 * fi + 2];

        const float* p0 = Vb + 3 * (size_t)i0;
        const float* p1 = Vb + 3 * (size_t)i1;
        const float* p2 = Vb + 3 * (size_t)i2;
        const float ax = p0[0], ay = p0[1], az = p0[2];
        const float bx = p1[0], by = p1[1], bz = p1[2];
        const float cx = p2[0], cy = p2[1], cz = p2[2];

        const float x0 = (ax + bx + cx) * (1.f / 3.f);
        const float x1 = (ay + by + cy) * (1.f / 3.f);
        const float x2 = (az + bz + cz) * (1.f / 3.f);

        const float e1x = bx - ax, e1y = by - ay, e1z = bz - az;
        const float e2x = cx - ax, e2y = cy - ay, e2z = cz - az;

        const float nx = 0.5f * (e1y * e2z - e1z * e2y);
        const float ny = 0.5f * (e1z * e2x - e1x * e2z);
        const float nz = 0.5f * (e1x * e2y - e1y * e2x);

        const float l2 = fmaxf(nx * nx + ny * ny + nz * nz, 1e-6f);
        const float rl = __builtin_amdgcn_rsqf(l2);
        const float L  = valid ? l2 * rl : 0.f;     // sqrt(l2), zeroed if pad face

        const float x3 = nx * rl, x4 = ny * rl, x5 = nz * rl;

        float* myrow = sh + tid * ROW;
#pragma unroll
        for (int jj = 0; jj < 16; ++jj) {
            float tj = wlds[96 + jj];
            tj = fmaf(x0, wlds[0 * 16 + jj], tj);
            tj = fmaf(x1, wlds[1 * 16 + jj], tj);
            tj = fmaf(x2, wlds[2 * 16 + jj], tj);
            tj = fmaf(x3, wlds[3 * 16 + jj], tj);
            tj = fmaf(x4, wlds[4 * 16 + jj], tj);
            tj = fmaf(x5, wlds[5 * 16 + jj], tj);
            myrow[jj] = fsig(tj);
        }
        myrow[16] = L;
        SL += L;

        __syncthreads();

        // ---- Phase C: layer2. Thread (kq,fg): 4 k-channels x 16 faces ----
#pragma unroll 4
        for (int ff = 0; ff < 16; ++ff) {
            const float* row = sh + (fg * 16 + ff) * ROW;
            float t0 = b2r.x, t1 = b2r.y, t2 = b2r.z, t3 = b2r.w;
#pragma unroll
            for (int jj = 0; jj < 16; ++jj) {
                const float hj = row[jj];
                t0 = fmaf(hj, w2r[jj].x, t0);
                t1 = fmaf(hj, w2r[jj].y, t1);
                t2 = fmaf(hj, w2r[jj].z, t2);
                t3 = fmaf(hj, w2r[jj].w, t3);
            }
            const float Lf = row[16];
            S0 = fmaf(fsig(t0), Lf, S0);
            S1 = fmaf(fsig(t1), Lf, S1);
            S2 = fmaf(fsig(t2), Lf, S2);
            S3 = fmaf(fsig(t3), Lf, S3);
        }
        __syncthreads();   // protect sh before next tile's writes
    }

    // ---- Block reduction ----
    // S: reduce across the 16 fg-threads sharing each kq. Reuse sh (free here).
    float4* red4 = (float4*)sh;
    red4[tid] = make_float4(S0, S1, S2, S3);

#pragma unroll
    for (int off = 32; off; off >>= 1)
        SL += __shfl_down(SL, off, 64);
    if (lane == 0) slred[wave] = SL;

    __syncthreads();

    if (tid < 64) {
        const int kk = tid;            // output channel
        const int kqq = kk >> 2, q = kk & 3;
        float s = 0.f;
#pragma unroll
        for (int fgi = 0; fgi < 16; ++fgi)
            s += sh[(fgi * 16 + kqq) * 4 + q];
        ws[((size_t)b * GPB + g) * 65 + kk] = s;
    }
    if (tid == 0) {
        float s = slred[0] + slred[1] + slred[2] + slred[3];
        ws[((size_t)b * GPB + g) * 65 + 64] = s;
    }
}

// Kernel 2: fold the GPB partials through W3/b3. One block per batch.
__global__ __launch_bounds__(128) void finalize_out(
    const float* __restrict__ ws,  // [B, GPB, 65]
    const float* __restrict__ W3,  // [64, CCLS]
    const float* __restrict__ b3,  // [CCLS]
    float* __restrict__ out)       // [B, CCLS]
{
    __shared__ float sm[65];
    const int b = blockIdx.x;
    const int tid = threadIdx.x;

    if (tid < 65) {
        float s = 0.f;
#pragma unroll 8
        for (int g = 0; g < GPB; ++g)
            s += ws[((size_t)b * GPB + g) * 65 + tid];
        sm[tid] = s;
    }
    __syncthreads();

    if (tid < CCLS) {
        float acc = b3[tid] * sm[64];
#pragma unroll
        for (int k = 0; k < 64; ++k)
            acc = fmaf(sm[k], W3[k * CCLS + tid], acc);
        out[b * CCLS + tid] = acc;
    }
}

extern "C" void kernel_launch(void* const* d_in, const int* in_sizes, int n_in,
                              void* d_out, int out_size, void* d_ws, size_t ws_size,
                              hipStream_t stream) {
    const float* V  = (const float*)d_in[0];
    const int*   F  = (const int*)  d_in[1];
    const float* W1 = (const float*)d_in[2];
    const float* b1 = (const float*)d_in[3];
    const float* W2 = (const float*)d_in[4];
    const float* b2 = (const float*)d_in[5];
    const float* W3 = (const float*)d_in[6];
    const float* b3 = (const float*)d_in[7];
    float* out = (float*)d_out;
    float* ws  = (float*)d_ws;     // needs B*GPB*65*4 = 532,480 bytes

    face_mlp_partial<<<B_ * GPB, TPB, 0, stream>>>(V, F, W1, b1, W2, b2, ws);
    finalize_out<<<B_, 128, 0, stream>>>(ws, W3, b3, out);
}

// Round 3
// 100.676 us; speedup vs baseline: 14.4789x; 1.4626x over previous
//
#include <hip/hip_runtime.h>
#include <hip/hip_bf16.h>

// Problem constants (match reference)
#define B_    32
#define NV_   50000
#define NF_   100000
#define CCLS  40
#define GPB   64                       // blocks per batch
#define TPB   256
#define NTILE ((NF_ + TPB - 1) / TPB)  // 391 face-tiles per batch

typedef __attribute__((ext_vector_type(8)))  short short8v;   // 8 bf16 = 4 VGPRs
typedef __attribute__((ext_vector_type(16))) float f32x16;    // MFMA 32x32 accum

__device__ __forceinline__ float fsig(float t) {
    return __builtin_amdgcn_rcpf(1.0f + __expf(-t));
}

__device__ __forceinline__ ushort f2bf(float x) {
    __hip_bfloat16 h = __float2bfloat16(x);   // RNE
    return *reinterpret_cast<ushort*>(&h);
}

// Kernel 1: per 256-face tile: phase A/B (geometry + layer1 -> bf16 LDS),
// phase C (layer2 on the MATRIX pipe: 32x32x16 bf16 MFMA, K=16 exact).
// Emits per-block partials ws[b][g][0..63]=sum sig(h2)[k]*L, ws[b][g][64]=sum L.
__global__ __launch_bounds__(TPB, 4) void face_mlp_partial(
    const float* __restrict__ V,   // [B,NV,3]
    const int*   __restrict__ F,   // [B,NF,3]
    const float* __restrict__ W1,  // [6,16]
    const float* __restrict__ b1,  // [16]
    const float* __restrict__ W2,  // [16,64]
    const float* __restrict__ b2,  // [64]
    float* __restrict__ ws)        // [B, GPB, 65]
{
    __shared__ __align__(16) ushort h1s[TPB * 16];  // bf16 h1, 32B/row (8KB)
    __shared__ float sLs[TPB];                      // L per face
    __shared__ float wlds[112];                     // W1(96)+b1(16)
    __shared__ float red[4][64];
    __shared__ float slred[4];

    const int i   = blockIdx.x;
    // XCD-aware mapping: block i -> XCD (i&7); each XCD owns 4 batches so the
    // 4 x 600KB V-slices stay resident in its 4MB L2.
    const int xcd = i & 7;
    const int j   = i >> 3;
    const int b   = xcd + 8 * (j >> 6);
    const int g   = j & 63;
    const int tid = threadIdx.x;
    const int lane  = tid & 63;
    const int wave  = tid >> 6;
    const int ln31  = lane & 31;
    const int halfk = lane >> 5;       // k-half for A/B fragments

    const float* Vb = V + (size_t)b * NV_ * 3;
    const int*   Fb = F + (size_t)b * NF_ * 3;

    if (tid < 96)       wlds[tid] = W1[tid];
    else if (tid < 112) wlds[tid] = b1[tid - 96];

    // B-fragments of W2 (loaded once): lane holds B[k=(halfk*8+i)][col=n*32+ln31]
    short8v w2f[2];
    float   b2c[2];
#pragma unroll
    for (int n = 0; n < 2; ++n) {
        const int col = n * 32 + ln31;
#pragma unroll
        for (int q = 0; q < 8; ++q)
            w2f[n][q] = (short)f2bf(W2[(halfk * 8 + q) * 64 + col]);
        b2c[n] = b2[col];
    }

    float S0 = 0.f, S1 = 0.f, SL = 0.f;

    __syncthreads();

    for (int t = g; t < NTILE; t += GPB) {
        // ---- Phase A/B: one face per thread: geometry + layer1 ----
        const int f      = t * TPB + tid;
        const bool valid = (f < NF_);
        const int fi     = valid ? f : 0;

        const int i0 = Fb[3 * fi + 0];
        const int i1 = Fb[3 * fi + 1];
        const int i2 = Fb[3 * fi + 2];

        const float* p0 = Vb + 3 * (size_t)i0;
        const float* p1 = Vb + 3 * (size_t)i1;
        const float* p2 = Vb + 3 * (size_t)i2;
        const float ax = p0[0], ay = p0[1], az = p0[2];
        const float bx = p1[0], by = p1[1], bz = p1[2];
        const float cx = p2[0], cy = p2[1], cz = p2[2];

        const float x0 = (ax + bx + cx) * (1.f / 3.f);
        const float x1 = (ay + by + cy) * (1.f / 3.f);
        const float x2 = (az + bz + cz) * (1.f / 3.f);

        const float e1x = bx - ax, e1y = by - ay, e1z = bz - az;
        const float e2x = cx - ax, e2y = cy - ay, e2z = cz - az;

        const float nx = 0.5f * (e1y * e2z - e1z * e2y);
        const float ny = 0.5f * (e1z * e2x - e1x * e2z);
        const float nz = 0.5f * (e1x * e2y - e1y * e2x);

        const float l2 = fmaxf(nx * nx + ny * ny + nz * nz, 1e-6f);
        const float rl = __builtin_amdgcn_rsqf(l2);
        const float L  = valid ? l2 * rl : 0.f;

        const float x3 = nx * rl, x4 = ny * rl, x5 = nz * rl;

        short8v hrow[2];
#pragma unroll
        for (int jj = 0; jj < 16; ++jj) {
            float tj = wlds[96 + jj];
            tj = fmaf(x0, wlds[0 * 16 + jj], tj);
            tj = fmaf(x1, wlds[1 * 16 + jj], tj);
            tj = fmaf(x2, wlds[2 * 16 + jj], tj);
            tj = fmaf(x3, wlds[3 * 16 + jj], tj);
            tj = fmaf(x4, wlds[4 * 16 + jj], tj);
            tj = fmaf(x5, wlds[5 * 16 + jj], tj);
            hrow[jj >> 3][jj & 7] = (short)f2bf(fsig(tj));
        }
        ((short8v*)h1s)[tid * 2 + 0] = hrow[0];
        ((short8v*)h1s)[tid * 2 + 1] = hrow[1];
        sLs[tid] = L;
        SL += L;

        __syncthreads();

        // ---- Phase C: layer2 via MFMA. Wave owns faces wave*64..+63 ----
#pragma unroll
        for (int m = 0; m < 2; ++m) {
            const int rowbase = wave * 64 + m * 32;
            // A-fragment: row = rowbase+ln31, k-half = halfk
            short8v a = *(const short8v*)(h1s + (rowbase + ln31) * 16 + halfk * 8);

            f32x16 c0, c1;
#pragma unroll
            for (int r = 0; r < 16; ++r) { c0[r] = b2c[0]; c1[r] = b2c[1]; }
            c0 = __builtin_amdgcn_mfma_f32_32x32x16_bf16(a, w2f[0], c0, 0, 0, 0);
            c1 = __builtin_amdgcn_mfma_f32_32x32x16_bf16(a, w2f[1], c1, 0, 0, 0);

            float Lv[16];
#pragma unroll
            for (int r = 0; r < 16; ++r)
                Lv[r] = sLs[rowbase + (r & 3) + 8 * (r >> 2) + 4 * halfk];
#pragma unroll
            for (int r = 0; r < 16; ++r) {
                S0 = fmaf(fsig(c0[r]), Lv[r], S0);
                S1 = fmaf(fsig(c1[r]), Lv[r], S1);
            }
        }
        __syncthreads();   // protect h1s/sLs before next tile's writes
    }

    // ---- Block reduction ----
    // Channel c=n*32+ln31: lanes l and l+32 hold the same channel.
    S0 += __shfl_down(S0, 32, 64);
    S1 += __shfl_down(S1, 32, 64);
#pragma unroll
    for (int off = 32; off; off >>= 1)
        SL += __shfl_down(SL, off, 64);

    if (lane < 32) {
        red[wave][ln31]      = S0;
        red[wave][32 + ln31] = S1;
    }
    if (lane == 0) slred[wave] = SL;
    __syncthreads();

    if (tid < 64) {
        float s = red[0][tid] + red[1][tid] + red[2][tid] + red[3][tid];
        ws[((size_t)b * GPB + g) * 65 + tid] = s;
    }
    if (tid == 0)
        ws[((size_t)b * GPB + g) * 65 + 64] = slred[0] + slred[1] + slred[2] + slred[3];
}

// Kernel 2: fold the GPB partials through W3/b3. One block per batch.
__global__ __launch_bounds__(128) void finalize_out(
    const float* __restrict__ ws,  // [B, GPB, 65]
    const float* __restrict__ W3,  // [64, CCLS]
    const float* __restrict__ b3,  // [CCLS]
    float* __restrict__ out)       // [B, CCLS]
{
    __shared__ float sm[65];
    const int b = blockIdx.x;
    const int tid = threadIdx.x;

    if (tid < 65) {
        float s = 0.f;
#pragma unroll 8
        for (int g = 0; g < GPB; ++g)
            s += ws[((size_t)b * GPB + g) * 65 + tid];
        sm[tid] = s;
    }
    __syncthreads();

    if (tid < CCLS) {
        float acc = b3[tid] * sm[64];
#pragma unroll
        for (int k = 0; k < 64; ++k)
            acc = fmaf(sm[k], W3[k * CCLS + tid], acc);
        out[b * CCLS + tid] = acc;
    }
}

extern "C" void kernel_launch(void* const* d_in, const int* in_sizes, int n_in,
                              void* d_out, int out_size, void* d_ws, size_t ws_size,
                              hipStream_t stream) {
    const float* V  = (const float*)d_in[0];
    const int*   F  = (const int*)  d_in[1];
    const float* W1 = (const float*)d_in[2];
    const float* b1 = (const float*)d_in[3];
    const float* W2 = (const float*)d_in[4];
    const float* b2 = (const float*)d_in[5];
    const float* W3 = (const float*)d_in[6];
    const float* b3 = (const float*)d_in[7];
    float* out = (float*)d_out;
    float* ws  = (float*)d_ws;     // needs B*GPB*65*4 = 532,480 bytes

    face_mlp_partial<<<B_ * GPB, TPB, 0, stream>>>(V, F, W1, b1, W2, b2, ws);
    finalize_out<<<B_, 128, 0, stream>>>(ws, W3, b3, out);
}